// Round 5
// baseline (160.557 us; speedup 1.0000x reference)
//
#include <hip/hip_runtime.h>
#include <hip/hip_bf16.h>

#define VOCAB 200000
#define EDIM  256

typedef __attribute__((ext_vector_type(4))) float  f32x4;
typedef __attribute__((ext_vector_type(8))) __bf16 bf16x8;

__device__ __forceinline__ __bf16 f2bf(float f) {
    unsigned u = __builtin_bit_cast(unsigned, f);
    u += 0x7FFFu + ((u >> 16) & 1u);           // round-to-nearest-even
    unsigned short s = (unsigned short)(u >> 16);
    return __builtin_bit_cast(__bf16, s);
}

// Pack B into MFMA fragment order (verified round 1).
// k = a*16 + b;  B[k][j] = core1[b, j, a], core1 is (16,256,16).
// bpk[(kk*16 + nt)*64 + lane] : lane l elem e = B[kk*32 + (l>>4)*8 + e][nt*16 + (l&15)]
__global__ void pack_b_kernel(const float* __restrict__ core1, bf16x8* __restrict__ bpk) {
    int t    = blockIdx.x * 256 + threadIdx.x;   // 0..8191
    int lane = t & 63;
    int nt   = (t >> 6) & 15;
    int kk   = t >> 10;
    int j     = nt * 16 + (lane & 15);
    int kbase = kk * 32 + ((lane >> 4) * 8);
    bf16x8 v;
#pragma unroll
    for (int e = 0; e < 8; ++e) {
        int k = kbase + e;
        int b = k & 15, a = k >> 4;
        v[e] = f2bf(core1[(b * 256 + j) * 16 + a]);
    }
    bpk[t] = v;
}

// Block = 1024 threads (16 waves): 256 gathered rows x 128 output cols.
// 64 KB LDS (one B col-half) + VGPR<=64 -> 2 blocks/CU = 32 waves/CU = 100%
// occupancy; TLP (8 waves/SIMD, each with depth-1 rolling A prefetch) hides
// the scattered-gather HBM latency. XCD-pair swizzle keeps both col-halves
// of a rowTile on one XCD so the A re-read is an L2 hit.
__global__ __launch_bounds__(1024, 8) void tr_embed_kernel(
        const int* __restrict__ x, const float* __restrict__ core0,
        const bf16x8* __restrict__ bpk, float* __restrict__ out) {
    __shared__ bf16x8 smem[4096];               // 64 KB: [kk 0..7][ntl 0..7][lane 0..63]
    const int tid  = threadIdx.x;
    const int lane = tid & 63;
    const int wave = tid >> 6;                  // 0..15

    // grid = 1600 = 8 XCDs * 200 slots (round-robin bid->XCD assumed; perf-only)
    const int xcd  = blockIdx.x & 7;
    const int slot = blockIdx.x >> 3;           // 0..199 on this XCD
    const int rowTile = xcd * 100 + (slot >> 1);  // 0..799
    const int colHalf = slot & 1;

    const int rowBase = rowTile * 256 + wave * 16;   // < 204800
    const int idx = x[rowBase + (lane & 15)];   // issue early

    // A gather: k = a*16+b; k-step kk covers a = 2kk + (half>>1), b = (half&1)*8 + e
    const int half = lane >> 4;                 // 0..3
    const float* aptr = core0 + ((long)(half >> 1) * VOCAB + idx) * 16 + (half & 1) * 8;
    const int KST = 2 * VOCAB * 16;             // floats per k-step (a advances by 2)

    // Issue k-step 0's A loads before the barrier (latency overlaps staging+drain).
    f32x4 pa = *(const f32x4*)(aptr);
    f32x4 pb = *(const f32x4*)(aptr + 4);

    // Stage this block's B half: 4096 frags * 16 B, coalesced (L2-resident) reads.
#pragma unroll
    for (int i = 0; i < 4; ++i) {
        int e   = i * 1024 + tid;               // 0..4095
        int kk  = e >> 9;
        int ntl = (e >> 6) & 7;
        int ln  = e & 63;
        smem[e] = bpk[(kk * 16 + colHalf * 8 + ntl) * 64 + ln];
    }

    __syncthreads();

    f32x4 acc[8] = {};
#pragma unroll
    for (int kk = 0; kk < 8; ++kk) {
        f32x4 ca = pa, cb = pb;
        if (kk < 7) {                           // depth-1 rolling prefetch
            pa = *(const f32x4*)(aptr + (long)(kk + 1) * KST);
            pb = *(const f32x4*)(aptr + (long)(kk + 1) * KST + 4);
        }
        bf16x8 af;
#pragma unroll
        for (int e = 0; e < 4; ++e) { af[e] = f2bf(ca[e]); af[e + 4] = f2bf(cb[e]); }

        const bf16x8* bs = smem + kk * 512 + lane;
#pragma unroll
        for (int ntl = 0; ntl < 8; ++ntl)
            acc[ntl] = __builtin_amdgcn_mfma_f32_16x16x32_bf16(af, bs[ntl * 64], acc[ntl], 0, 0, 0);
    }

    // C/D layout: col = lane&15, row = (lane>>4)*4 + reg (verified)
    float* obase = out + (long)rowBase * 256 + colHalf * 128 + (lane & 15);
#pragma unroll
    for (int ntl = 0; ntl < 8; ++ntl) {
#pragma unroll
        for (int e = 0; e < 4; ++e) {
            obase[(half * 4 + e) * 256 + ntl * 16] = acc[ntl][e];
        }
    }
}

extern "C" void kernel_launch(void* const* d_in, const int* in_sizes, int n_in,
                              void* d_out, int out_size, void* d_ws, size_t ws_size,
                              hipStream_t stream) {
    const int*   x     = (const int*)d_in[0];
    const float* core0 = (const float*)d_in[1];
    const float* core1 = (const float*)d_in[2];
    float* out = (float*)d_out;
    bf16x8* bpk = (bf16x8*)d_ws;                // 128 KB scratch

    pack_b_kernel<<<32, 256, 0, stream>>>(core1, bpk);
    // 800 rowTiles * 2 col-halves = 1600 blocks (= 8 XCDs * 200 slots)
    tr_embed_kernel<<<1600, 1024, 0, stream>>>(x, core0, bpk, out);
}

// Round 6
// 121.244 us; speedup vs baseline: 1.3242x; 1.3242x over previous
//
#include <hip/hip_runtime.h>
#include <hip/hip_bf16.h>

#define VOCAB 200000
#define EDIM  256

typedef __attribute__((ext_vector_type(4))) float  f32x4;
typedef __attribute__((ext_vector_type(8))) __bf16 bf16x8;

typedef const __attribute__((address_space(1))) unsigned int* gas_u32p;
typedef __attribute__((address_space(3))) unsigned int* las_u32p;

__device__ __forceinline__ __bf16 f2bf(float f) {
    unsigned u = __builtin_bit_cast(unsigned, f);
    u += 0x7FFFu + ((u >> 16) & 1u);           // round-to-nearest-even
    unsigned short s = (unsigned short)(u >> 16);
    return __builtin_bit_cast(__bf16, s);
}

// Pack B into MFMA fragment order (verified round 1).
// k = a*16 + b;  B[k][j] = core1[b, j, a], core1 is (16,256,16).
// bpk[(kk*16 + nt)*64 + lane] : lane l elem e = B[kk*32 + (l>>4)*8 + e][nt*16 + (l&15)]
__global__ void pack_b_kernel(const float* __restrict__ core1, bf16x8* __restrict__ bpk) {
    int t    = blockIdx.x * 256 + threadIdx.x;   // 0..8191
    int lane = t & 63;
    int nt   = (t >> 6) & 15;
    int kk   = t >> 10;
    int j     = nt * 16 + (lane & 15);
    int kbase = kk * 32 + ((lane >> 4) * 8);
    bf16x8 v;
#pragma unroll
    for (int e = 0; e < 8; ++e) {
        int k = kbase + e;
        int b = k & 15, a = k >> 4;
        v[e] = f2bf(core1[(b * 256 + j) * 16 + a]);
    }
    bpk[t] = v;
}

// Block = 512 threads (8 waves): 128 gathered rows x ALL 256 output cols.
// A is loaded ONCE per block: all 16 scattered dwordx4 issued up front (8 KB in
// flight per wave), converted once to af[8] (32 VGPR) and reused for both B
// col-halves, which are staged sequentially into one 64 KB LDS buffer via
// global_load_lds (zero VGPR). Latency paid once per block, not per k-step.
__global__ __launch_bounds__(512, 4) void tr_embed_kernel(
        const int* __restrict__ x, const float* __restrict__ core0,
        const bf16x8* __restrict__ bpk, float* __restrict__ out) {
    __shared__ bf16x8 smem[4096];               // 64 KB: [kk 0..7][ntl 0..7][lane 0..63]
    const int tid  = threadIdx.x;
    const int lane = tid & 63;
    const int wave = tid >> 6;                  // 0..7

    const int rowBase = blockIdx.x * 128 + wave * 16;   // < 204800
    const int idx = x[rowBase + (lane & 15)];

    // A gather: k = a*16+b; k-step kk covers a = 2kk + (half>>1), b = (half&1)*8 + e
    const int half = lane >> 4;                 // 0..3
    const float* aptr = core0 + ((long)(half >> 1) * VOCAB + idx) * 16 + (half & 1) * 8;
    const long KST = 2L * VOCAB * 16;           // floats per k-step (a advances by 2)

    // ---- stage B col-half 0 into LDS (no VGPR round-trip; vmcnt queue) ----
    // per wave i-th inst: src = bpk[(i*16 + wave)*64 + lane], dst = smem + i*512 + wave*64
#pragma unroll
    for (int i = 0; i < 8; ++i) {
        const bf16x8* src = bpk + (i * 16 + 0 * 8 + wave) * 64 + lane;
        __builtin_amdgcn_global_load_lds((gas_u32p)src, (las_u32p)(smem + i * 512 + wave * 64),
                                         16, 0, 0);
    }

    // ---- issue ALL A loads up front (burst; nothing can sink them) ----
    f32x4 pa[8], pb[8];
#pragma unroll
    for (int k = 0; k < 8; ++k) {
        pa[k] = *(const f32x4*)(aptr + k * KST);
        pb[k] = *(const f32x4*)(aptr + k * KST + 4);
    }
    // ---- convert once; af lives across both phases ----
    bf16x8 af[8];
#pragma unroll
    for (int k = 0; k < 8; ++k) {
#pragma unroll
        for (int e = 0; e < 4; ++e) { af[k][e] = f2bf(pa[k][e]); af[k][e + 4] = f2bf(pb[k][e]); }
    }

    __syncthreads();                            // drains vmcnt: B0 in LDS, A converted

    float* obase = out + (long)rowBase * 256 + (lane & 15);

    // ---- phase 1: cols 0..127 ----
    {
        f32x4 acc[8] = {};
#pragma unroll
        for (int kk = 0; kk < 8; ++kk) {
            const bf16x8* bs = smem + kk * 512 + lane;
#pragma unroll
            for (int ntl = 0; ntl < 8; ++ntl)
                acc[ntl] = __builtin_amdgcn_mfma_f32_16x16x32_bf16(af[kk], bs[ntl * 64], acc[ntl], 0, 0, 0);
        }
#pragma unroll
        for (int ntl = 0; ntl < 8; ++ntl)
#pragma unroll
            for (int e = 0; e < 4; ++e)
                obase[(half * 4 + e) * 256 + ntl * 16] = acc[ntl][e];
    }

    __syncthreads();                            // all waves done reading half 0

    // ---- stage B col-half 1 into same LDS ----
#pragma unroll
    for (int i = 0; i < 8; ++i) {
        const bf16x8* src = bpk + (i * 16 + 8 + wave) * 64 + lane;
        __builtin_amdgcn_global_load_lds((gas_u32p)src, (las_u32p)(smem + i * 512 + wave * 64),
                                         16, 0, 0);
    }

    __syncthreads();                            // vmcnt(0) drain before reads

    // ---- phase 2: cols 128..255 (same af) ----
    {
        f32x4 acc[8] = {};
#pragma unroll
        for (int kk = 0; kk < 8; ++kk) {
            const bf16x8* bs = smem + kk * 512 + lane;
#pragma unroll
            for (int ntl = 0; ntl < 8; ++ntl)
                acc[ntl] = __builtin_amdgcn_mfma_f32_16x16x32_bf16(af[kk], bs[ntl * 64], acc[ntl], 0, 0, 0);
        }
#pragma unroll
        for (int ntl = 0; ntl < 8; ++ntl)
#pragma unroll
            for (int e = 0; e < 4; ++e)
                obase[(half * 4 + e) * 256 + 128 + ntl * 16] = acc[ntl][e];
    }
}

extern "C" void kernel_launch(void* const* d_in, const int* in_sizes, int n_in,
                              void* d_out, int out_size, void* d_ws, size_t ws_size,
                              hipStream_t stream) {
    const int*   x     = (const int*)d_in[0];
    const float* core0 = (const float*)d_in[1];
    const float* core1 = (const float*)d_in[2];
    float* out = (float*)d_out;
    bf16x8* bpk = (bf16x8*)d_ws;                // 128 KB scratch

    pack_b_kernel<<<32, 256, 0, stream>>>(core1, bpk);
    // 204800 rows / 128 rows-per-block = 1600 blocks, full 256 cols per block
    tr_embed_kernel<<<1600, 512, 0, stream>>>(x, core0, bpk, out);
}